// Round 15
// baseline (228.603 us; speedup 1.0000x reference)
//
#include <hip/hip_runtime.h>
#include <hip/hip_bf16.h>
#include <stdint.h>

// Problem constants (fixed by setup_inputs)
#define B_   64
#define H_   512
#define W_   512
#define S_N  1024      // n_segments
#define E_N  768       // embed_dim
#define K_N  768       // C*box*box = 3*16*16
#define HALF 8

typedef short bf16x8 __attribute__((ext_vector_type(8)));
typedef float f32x4  __attribute__((ext_vector_type(4)));
typedef float f32x4u __attribute__((ext_vector_type(4), aligned(4)));  // 4B-aligned float4

__device__ __forceinline__ unsigned short f2bf(float f) {
  union { float f; unsigned u; } v; v.f = f;
  unsigned u = v.u;
  u += 0x7FFF + ((u >> 16) & 1);   // RNE
  return (unsigned short)(u >> 16);
}

// ------ Phase 1 (merged): per-(b,s) packed sums (blocks 0..1023) +
//        conv_w fp32->bf16 (blocks 1024..1599) ---------------------------------
__global__ void k_accum_convw(const int* __restrict__ seg,
                              unsigned long long* __restrict__ partials,
                              const float* __restrict__ w,
                              unsigned short* __restrict__ wb) {
  __shared__ unsigned long long ls[S_N];
  const int bid = blockIdx.x;
  const int tid = threadIdx.x;
  if (bid >= 1024) {                 // conv_w conversion: 147,456 float4s
    int idx = (bid - 1024) * 256 + tid;
    float4 v = ((const float4*)w)[idx];
    ushort4 o;
    o.x = f2bf(v.x); o.y = f2bf(v.y); o.z = f2bf(v.z); o.w = f2bf(v.w);
    ((ushort4*)wb)[idx] = o;
    return;
  }
  const int xblk = bid & 15;         // 0..15
  const int b    = bid >> 4;         // 0..63
  for (int i = tid; i < S_N; i += 256) ls[i] = 0ULL;
  __syncthreads();
  const int pix0 = xblk * 16384;
  const int4* segb = (const int4*)(seg + (size_t)b * (H_ * W_) + pix0);
  for (int it = 0; it < 16; ++it) {
    int4 s4 = segb[it * 256 + tid];
    int p0 = pix0 + (it * 256 + tid) * 4;
    unsigned long long base = ((unsigned long long)(unsigned)(p0 >> 9) << 39)
                            | ((unsigned long long)(unsigned)(p0 & (W_ - 1)) << 15)
                            | 1ULL;
    #pragma unroll
    for (int j = 0; j < 4; ++j) {
      int s = (&s4.x)[j];
      s = ((unsigned)s < S_N) ? s : 0;
      atomicAdd(&ls[s], base + ((unsigned long long)j << 15));
    }
  }
  __syncthreads();
  unsigned long long* gp = partials + ((size_t)b * 16 + xblk) * S_N;
  for (int s = tid; s < S_N; s += 256) gp[s] = ls[s];
}

// ------ Phase 2: centroid reduce + gather, 4-lane x float4 / 8B stores --------
__global__ __launch_bounds__(256) void k_patch4(const float* __restrict__ img,
                                                const unsigned long long* __restrict__ partials,
                                                unsigned short* __restrict__ A) {
  const int g  = threadIdx.x >> 4;    // 0..15 : patch slot in block
  const int ln = threadIdx.x & 15;
  const int m  = blockIdx.x * 16 + g;
  const int b  = m >> 10;
  const int s  = m & (S_N - 1);
  unsigned long long v = partials[((size_t)b * 16 + ln) * S_N + s];
  unsigned c  = (unsigned)(v & 0x7FFFULL);
  unsigned sx = (unsigned)((v >> 15) & 0xFFFFFFULL);
  unsigned sy = (unsigned)(v >> 39);
  #pragma unroll
  for (int off = 8; off; off >>= 1) {
    c  += __shfl_xor(c,  off, 16);
    sx += __shfl_xor(sx, off, 16);
    sy += __shfl_xor(sy, off, 16);
  }
  int xmin = 0, ymin = 0;
  if (c > 0) {
    float cf = (float)c;
    xmin = (int)floorf((float)sx / cf);   // IEEE f32 div of exact ints == ref
    ymin = (int)floorf((float)sy / cf);
  }
  const int srw = ln >> 2;          // 0..3 : sub-row within 4-row group
  const int x4  = (ln & 3) * 4;     // 0,4,8,12 : x-offset of this lane's float4
  const float* ib = img + (size_t)b * 3 * H_ * W_;
  unsigned short* Am = A + (size_t)m * K_N;

  if (xmin >= HALF && xmin <= W_ - HALF && ymin >= HALF && ymin <= H_ - HALF) {
    const float* p0 = ib + (size_t)(ymin - HALF) * W_ + (xmin - HALF);
    #pragma unroll
    for (int r0 = 0; r0 < 12; ++r0) {
      int r = r0 * 4 + srw;               // 0..47 = c*16 + h
      int cch = r >> 4, h = r & 15;
      f32x4u vv = *(const f32x4u*)(p0 + (size_t)((cch << 9) + h) * W_ + x4);
      ushort4 o;
      o.x = f2bf(vv[0]); o.y = f2bf(vv[1]); o.z = f2bf(vv[2]); o.w = f2bf(vv[3]);
      *(ushort4*)(Am + r * 16 + x4) = o;
    }
  } else {
    #pragma unroll
    for (int r0 = 0; r0 < 12; ++r0) {
      int r = r0 * 4 + srw;
      int cch = r >> 4, h = r & 15;
      int y = ymin - HALF + h;
      bool yok = (unsigned)y < H_;
      const float* rp = ib + (size_t)((cch << 9) + (yok ? y : 0)) * W_;
      ushort4 o;
      unsigned short* op = (unsigned short*)&o;
      #pragma unroll
      for (int j = 0; j < 4; ++j) {
        int x = xmin - HALF + x4 + j;
        float pv = (yok && (unsigned)x < W_) ? rp[x] : 0.f;
        op[j] = f2bf(pv);
      }
      *(ushort4*)(Am + r * 16 + x4) = o;
    }
  }
}

// ------ Phase 3: PERSISTENT 256x256 8-phase GEMM, 256 blocks (1/CU) -----------
// r13's null result: all K-loop schedules land at ~115us -> the cost is OUTSIDE
// the K-loop: block turnover (LDS 128KB = 1 block/CU, next block waits for the
// 262KB C-burst to drain, x3 rounds) + A re-fetch. Fix: 256 blocks, bm fixed
// per block (65536/256 = 256 tiles = 1/CU, zero turnover), loop bn=0,1,2 with
// the proven r11 8-phase core. Epilogue OVERLAP: each acc quadrant is final
// after its last tail MFMA -> its stores issue inside the remaining tail
// phases; next tile's prologue vmcnt(4) (in-order) confirms older stores
// drained, so the counted-vmcnt ledger stays valid. A panel L2-hot for bn=1,2.
__global__ __launch_bounds__(512) void k_gemmp(
    const unsigned short* __restrict__ Amat,
    const unsigned short* __restrict__ Bmat,
    float* __restrict__ out) {
  __shared__ unsigned short As[2][256 * 64];
  __shared__ unsigned short Bs[2][256 * 64];
  const int tid  = threadIdx.x;
  const int wave = tid >> 6;
  const int lane = tid & 63;

  // bijective XCD remap: 256 blocks = 8 XCDs x 32
  const int bm = (blockIdx.x & 7) * 32 + (blockIdx.x >> 3);   // 0..255
  const int gm0 = bm * 256;
  int gn0 = 0;                        // varies over t; lambdas capture by ref

  const int wr = wave >> 2;          // 0..1
  const int wc = wave & 3;           // 0..3
  const int rlo  = lane & 15;
  const int rsel = lane & 7;
  const int sub  = lane >> 4;        // 0..3
  int swz[2];
  swz[0] = ((0 + sub) ^ rsel) * 8;   // shorts offset, kk=0
  swz[1] = ((4 + sub) ^ rsel) * 8;   // kk=1

  const int srow = lane >> 3;             // row within 8-row group
  const int sch  = (lane & 7) ^ srow;     // pre-swizzled source chunk

  f32x4 acc[8][4];
  #pragma unroll
  for (int i = 0; i < 8; ++i)
    #pragma unroll
    for (int j = 0; j < 4; ++j)
      acc[i][j] = (f32x4){0.f, 0.f, 0.f, 0.f};

  auto stageA = [&](int buf, int mh, int k0) {
    #pragma unroll
    for (int l = 0; l < 2; ++l) {
      int idx = wave * 2 + l;                                // 0..15
      int rowbase = mh * 64 + (idx >> 3) * 128 + (idx & 7) * 8;
      const unsigned short* g = Amat + (size_t)(gm0 + rowbase + srow) * K_N + k0 + sch * 8;
      __builtin_amdgcn_global_load_lds((const __attribute__((address_space(1))) void*)g,
        (__attribute__((address_space(3))) void*)&As[buf][rowbase * 64], 16, 0, 0);
    }
  };
  auto stageB = [&](int buf, int nh, int k0) {
    #pragma unroll
    for (int l = 0; l < 2; ++l) {
      int idx = wave * 2 + l;
      int rowbase = (idx >> 2) * 64 + nh * 32 + (idx & 3) * 8;
      const unsigned short* g = Bmat + (size_t)(gn0 + rowbase + srow) * K_N + k0 + sch * 8;
      __builtin_amdgcn_global_load_lds((const __attribute__((address_space(1))) void*)g,
        (__attribute__((address_space(3))) void*)&Bs[buf][rowbase * 64], 16, 0, 0);
    }
  };

  const int row0 = gm0 + wr * 128 + (lane >> 4) * 4;
  // store one finished quadrant (4x2 frags) and reset it for the next tile
  auto storeQ = [&](int mi0, int ni0) {
    const int col0 = gn0 + wc * 64 + (lane & 15);
    #pragma unroll
    for (int mi = 0; mi < 4; ++mi)
      #pragma unroll
      for (int ni = 0; ni < 2; ++ni) {
        #pragma unroll
        for (int r = 0; r < 4; ++r)
          out[(size_t)(row0 + (mi0 + mi) * 16 + r) * E_N + (col0 + (ni0 + ni) * 16)]
              = acc[mi0 + mi][ni0 + ni][r];
        acc[mi0 + mi][ni0 + ni] = (f32x4){0.f, 0.f, 0.f, 0.f};
      }
  };

  bf16x8 a[4][2], b[2][2];

#define LOAD_A(BUF, MH) \
  _Pragma("unroll") for (int mi = 0; mi < 4; ++mi) \
  _Pragma("unroll") for (int kk = 0; kk < 2; ++kk) \
    a[mi][kk] = *(const bf16x8*)&As[BUF][(wr * 128 + (MH) * 64 + mi * 16 + rlo) * 64 + swz[kk]];
#define LOAD_B(BUF, NH) \
  _Pragma("unroll") for (int ni = 0; ni < 2; ++ni) \
  _Pragma("unroll") for (int kk = 0; kk < 2; ++kk) \
    b[ni][kk] = *(const bf16x8*)&Bs[BUF][(wc * 64 + (NH) * 32 + ni * 16 + rlo) * 64 + swz[kk]];
#define MFMA_Q(MI0, NI0) \
  __builtin_amdgcn_s_setprio(1); \
  _Pragma("unroll") for (int mi = 0; mi < 4; ++mi) \
  _Pragma("unroll") for (int ni = 0; ni < 2; ++ni) \
  _Pragma("unroll") for (int kk = 0; kk < 2; ++kk) \
    acc[(MI0) + mi][(NI0) + ni] = __builtin_amdgcn_mfma_f32_16x16x32_bf16( \
        a[mi][kk], b[ni][kk], acc[(MI0) + mi][(NI0) + ni], 0, 0, 0); \
  __builtin_amdgcn_s_setprio(0);
#define SYNC_MFMA \
  __builtin_amdgcn_s_barrier(); \
  asm volatile("s_waitcnt lgkmcnt(0)" ::: "memory"); \
  __builtin_amdgcn_sched_barrier(0);
#define ENDPH __builtin_amdgcn_s_barrier();

  for (int t = 0; t < 3; ++t) {
    gn0 = t * 256;

    // Prologue: tile0 into buf0; tile1's hA0,hB1 into buf1. vmcnt(4) leaves the
    // 4 newest loads outstanding; any older epilogue stores (t>0) must have
    // retired below the threshold first (in-order count) -> stores drained.
    stageA(0, 0, 0); stageA(0, 1, 0); stageB(0, 0, 0); stageB(0, 1, 0);
    stageA(1, 0, 64); stageB(1, 1, 64);
    asm volatile("s_waitcnt vmcnt(4)" ::: "memory");
    __builtin_amdgcn_s_barrier();

    for (int i = 0; i < 5; ++i) {
      const int kB = (2 * i + 1) * 64;
      const int kC = (2 * i + 2) * 64;
      const int kD = (2 * i + 3) * 64;
      // P1
      LOAD_A(0, 0); LOAD_B(0, 0);
      stageB(1, 0, kB);
      SYNC_MFMA; MFMA_Q(0, 0); ENDPH;
      // P2
      LOAD_B(0, 1);
      stageA(1, 1, kB);
      SYNC_MFMA; MFMA_Q(0, 2); ENDPH;
      // P3
      LOAD_A(0, 1);
      stageA(0, 0, kC);
      SYNC_MFMA; MFMA_Q(4, 2); ENDPH;
      // P4
      LOAD_B(0, 0);
      stageB(0, 1, kC);
      asm volatile("s_waitcnt vmcnt(4)" ::: "memory");
      SYNC_MFMA; MFMA_Q(4, 0); ENDPH;
      // P5
      LOAD_A(1, 0); LOAD_B(1, 0);
      stageB(0, 0, kC);
      SYNC_MFMA; MFMA_Q(0, 0); ENDPH;
      // P6
      LOAD_B(1, 1);
      stageA(0, 1, kC);
      SYNC_MFMA; MFMA_Q(0, 2); ENDPH;
      // P7
      LOAD_A(1, 1);
      stageA(1, 0, kD);
      SYNC_MFMA; MFMA_Q(4, 2); ENDPH;
      // P8
      LOAD_B(1, 0);
      stageB(1, 1, kD);
      asm volatile("s_waitcnt vmcnt(4)" ::: "memory");
      SYNC_MFMA; MFMA_Q(4, 0); ENDPH;
    }

    // Tail: tiles 10 (buf0), 11 (buf1); epilogue stores interleaved into
    // T6/T7/T8/post (each quadrant final after its last MFMA).
    {
      const int k11 = 11 * 64;
      // T1
      LOAD_A(0, 0); LOAD_B(0, 0);
      stageB(1, 0, k11);
      SYNC_MFMA; MFMA_Q(0, 0); ENDPH;
      // T2
      LOAD_B(0, 1);
      stageA(1, 1, k11);
      SYNC_MFMA; MFMA_Q(0, 2); ENDPH;
      // T3
      LOAD_A(0, 1);
      SYNC_MFMA; MFMA_Q(4, 2); ENDPH;
      // T4: full load drain (stores not yet issued this tile)
      LOAD_B(0, 0);
      asm volatile("s_waitcnt vmcnt(0)" ::: "memory");
      SYNC_MFMA; MFMA_Q(4, 0); ENDPH;
      // T5
      LOAD_A(1, 0); LOAD_B(1, 0);
      SYNC_MFMA; MFMA_Q(0, 0); ENDPH;       // acc[0..3][0..1] final
      // T6
      LOAD_B(1, 1);
      storeQ(0, 0);
      SYNC_MFMA; MFMA_Q(0, 2); ENDPH;       // acc[0..3][2..3] final
      // T7
      LOAD_A(1, 1);
      storeQ(0, 2);
      SYNC_MFMA; MFMA_Q(4, 2); ENDPH;       // acc[4..7][2..3] final
      // T8
      LOAD_B(1, 0);
      storeQ(4, 2);
      SYNC_MFMA; MFMA_Q(4, 0); ENDPH;       // acc[4..7][0..1] final
      storeQ(4, 0);
    }
  }
#undef LOAD_A
#undef LOAD_B
#undef MFMA_Q
#undef SYNC_MFMA
#undef ENDPH
}

extern "C" void kernel_launch(void* const* d_in, const int* in_sizes, int n_in,
                              void* d_out, int out_size, void* d_ws, size_t ws_size,
                              hipStream_t stream) {
  const float* img = (const float*)d_in[0];
  const int*   seg = (const int*)d_in[1];
  const float* cw  = (const float*)d_in[2];
  float* out = (float*)d_out;
  char* ws = (char*)d_ws;

  unsigned long long* partials = (unsigned long long*)ws;    // 8,388,608 B
  unsigned short* Bmat = (unsigned short*)(ws + 8388608);    // 1,179,648 B
  unsigned short* Amat = (unsigned short*)(ws + 9568256);    // 100,663,296 B

  k_accum_convw<<<1600, 256, 0, stream>>>(seg, partials, cw, Bmat);
  k_patch4<<<4096, 256, 0, stream>>>(img, partials, Amat);
  k_gemmp<<<256, 512, 0, stream>>>(Amat, Bmat, out);
}

// Round 17
// 162.334 us; speedup vs baseline: 1.4082x; 1.4082x over previous
//
#include <hip/hip_runtime.h>
#include <hip/hip_bf16.h>
#include <stdint.h>

// Problem constants (fixed by setup_inputs)
#define B_   64
#define H_   512
#define W_   512
#define S_N  1024      // n_segments
#define E_N  768       // embed_dim
#define K_N  768       // C*box*box = 3*16*16
#define HALF 8

typedef short bf16x8 __attribute__((ext_vector_type(8)));
typedef float f32x4  __attribute__((ext_vector_type(4)));
typedef float f32x4u __attribute__((ext_vector_type(4), aligned(4)));  // 4B-aligned float4

__device__ __forceinline__ unsigned short f2bf(float f) {
  union { float f; unsigned u; } v; v.f = f;
  unsigned u = v.u;
  u += 0x7FFF + ((u >> 16) & 1);   // RNE
  return (unsigned short)(u >> 16);
}

// ------ Phase 1 (merged): per-(b,s) packed sums (blocks 0..1023) +
//        conv_w fp32->bf16 (blocks 1024..1599) ---------------------------------
__global__ void k_accum_convw(const int* __restrict__ seg,
                              unsigned long long* __restrict__ partials,
                              const float* __restrict__ w,
                              unsigned short* __restrict__ wb) {
  __shared__ unsigned long long ls[S_N];
  const int bid = blockIdx.x;
  const int tid = threadIdx.x;
  if (bid >= 1024) {                 // conv_w conversion: 147,456 float4s
    int idx = (bid - 1024) * 256 + tid;
    float4 v = ((const float4*)w)[idx];
    ushort4 o;
    o.x = f2bf(v.x); o.y = f2bf(v.y); o.z = f2bf(v.z); o.w = f2bf(v.w);
    ((ushort4*)wb)[idx] = o;
    return;
  }
  const int xblk = bid & 15;         // 0..15
  const int b    = bid >> 4;         // 0..63
  for (int i = tid; i < S_N; i += 256) ls[i] = 0ULL;
  __syncthreads();
  const int pix0 = xblk * 16384;
  const int4* segb = (const int4*)(seg + (size_t)b * (H_ * W_) + pix0);
  for (int it = 0; it < 16; ++it) {
    int4 s4 = segb[it * 256 + tid];
    int p0 = pix0 + (it * 256 + tid) * 4;
    unsigned long long base = ((unsigned long long)(unsigned)(p0 >> 9) << 39)
                            | ((unsigned long long)(unsigned)(p0 & (W_ - 1)) << 15)
                            | 1ULL;
    #pragma unroll
    for (int j = 0; j < 4; ++j) {
      int s = (&s4.x)[j];
      s = ((unsigned)s < S_N) ? s : 0;
      atomicAdd(&ls[s], base + ((unsigned long long)j << 15));
    }
  }
  __syncthreads();
  unsigned long long* gp = partials + ((size_t)b * 16 + xblk) * S_N;
  for (int s = tid; s < S_N; s += 256) gp[s] = ls[s];
}

// ------ Phase 2: FUSED coalesced-gather + 256x256 single-buffer GEMM ----------
// Based on r10's k_gemms (proven correct, 117us). Amat is never materialized:
// per K-tile, A is gathered COALESCED from img (8 consecutive lanes = one
// patch's 4 rows, 2x f32x4u per lane -> <=32 img rows / 64B segments per wave
// instr — the patch4 pattern, NOT r6's 64-scattered-rows one), converted, and
// ds_write_b128'd with the T2 XOR swizzle (write-side swizzle legal: ds path).
// Gather latency is absorbed by the phase slack (gemm phases are ~72% stall).
// Per-block patch coords computed once into LDS from partials.
// lgkmcnt(0)+vmcnt(0) precede the publish barrier (write-visibility safe).
__global__ __launch_bounds__(512) void k_gemmfg(
    const float* __restrict__ img,
    const unsigned long long* __restrict__ partials,
    const unsigned short* __restrict__ Bmat,
    float* __restrict__ out) {
  __shared__ unsigned short As[256 * 64];   // 32 KB
  __shared__ unsigned short Bs[256 * 64];   // 32 KB
  __shared__ int2 pc[256];                  // per-patch (cx0, cy0) = min corner
  const int tid  = threadIdx.x;
  const int wave = tid >> 6;
  const int lane = tid & 63;

  // bijective XCD remap: 768 blocks = 8 XCDs x 96; bn fastest
  const int virt = (blockIdx.x & 7) * 96 + (blockIdx.x >> 3);
  const int bm = virt / 3;
  const int bn = virt - bm * 3;
  const int gm0 = bm * 256;
  const int gn0 = bn * 256;
  const int b   = bm >> 2;                  // all 256 patches share batch b
  const float* ib = img + (size_t)b * 3 * H_ * W_;

  // ---- one-time: coords for this block's 256 patches (tid < 256) ----
  if (tid < 256) {
    const int s = (gm0 + tid) & (S_N - 1);
    unsigned c = 0, sx = 0, sy = 0;
    #pragma unroll
    for (int x = 0; x < 16; ++x) {
      unsigned long long v = partials[((size_t)b * 16 + x) * S_N + s];
      c  += (unsigned)(v & 0x7FFFULL);
      sx += (unsigned)((v >> 15) & 0xFFFFFFULL);
      sy += (unsigned)(v >> 39);
    }
    int xmin = 0, ymin = 0;
    if (c > 0) {
      float cf = (float)c;
      xmin = (int)floorf((float)sx / cf);   // IEEE f32 div of exact ints == ref
      ymin = (int)floorf((float)sy / cf);
    }
    pc[tid] = make_int2(xmin - HALF, ymin - HALF);
  }

  const int wr = wave >> 2;          // 0..1 : wave row (128 rows)
  const int wc = wave & 3;           // 0..3 : wave col (64 cols)
  const int rlo  = lane & 15;
  const int rsel = lane & 7;
  const int sub  = lane >> 4;        // 0..3
  int swz[2];
  swz[0] = ((0 + sub) ^ rsel) * 8;   // shorts offset, kk=0
  swz[1] = ((4 + sub) ^ rsel) * 8;   // kk=1

  f32x4 acc[8][4];
  #pragma unroll
  for (int i = 0; i < 8; ++i)
    #pragma unroll
    for (int j = 0; j < 4; ++j)
      acc[i][j] = (f32x4){0.f, 0.f, 0.f, 0.f};

  __syncthreads();                   // pc ready (also first-tile read fence)

  for (int kt = 0; kt < 12; ++kt) {
    const int k0 = kt * 64;

    // B stage via global_load_lds (r10-proven partition + T2 source swizzle)
    #pragma unroll
    for (int i = 0; i < 4; ++i) {
      int seg = i * 512 + tid;
      int row = seg >> 3;
      int csrc = (seg & 7) ^ (row & 7);
      const unsigned short* g = Bmat + (size_t)(gn0 + row) * K_N + k0 + csrc * 8;
      __builtin_amdgcn_global_load_lds((const __attribute__((address_space(1))) void*)g,
        (__attribute__((address_space(3))) void*)&Bs[(i * 512 + wave * 64) * 8], 16, 0, 0);
    }

    // A gather: 4 chunks/thread; chunk (row, cc) = 8 bf16 = one (c,h) half-row.
    // 8 consecutive lanes share a patch -> coalesced 64B segments.
    f32x4 ga[4][2];
    #pragma unroll
    for (int i = 0; i < 4; ++i) {
      int seg = i * 512 + tid;
      int row = seg >> 3;            // patch index in tile
      int cc  = seg & 7;
      int k = k0 + cc * 8;
      int ch = k >> 8, h = (k >> 4) & 15, w0 = k & 15;
      int2 p = pc[row];
      int y  = p.y + h;
      int x0 = p.x + w0;
      if (p.x >= 0 && p.x <= W_ - 16 && p.y >= 0 && p.y <= H_ - 16) {
        const float* rp = ib + (size_t)((ch << 9) + y) * W_ + x0;
        ga[i][0] = *(const f32x4u*)rp;
        ga[i][1] = *(const f32x4u*)(rp + 4);
      } else {                       // rare edge patch: masked scalar
        bool yok = (unsigned)y < H_;
        const float* rp = ib + (size_t)((ch << 9) + (yok ? y : 0)) * W_;
        f32x4 lo, hi;
        #pragma unroll
        for (int j = 0; j < 4; ++j) {
          int x = x0 + j;
          lo[j] = (yok && (unsigned)x < W_) ? rp[x] : 0.f;
        }
        #pragma unroll
        for (int j = 0; j < 4; ++j) {
          int x = x0 + 4 + j;
          hi[j] = (yok && (unsigned)x < W_) ? rp[x] : 0.f;
        }
        ga[i][0] = lo;
        ga[i][1] = hi;
      }
    }
    // convert + swizzled LDS write
    #pragma unroll
    for (int i = 0; i < 4; ++i) {
      int seg = i * 512 + tid;
      int row = seg >> 3;
      int cc  = seg & 7;
      bf16x8 t;
      t[0] = (short)f2bf(ga[i][0][0]); t[1] = (short)f2bf(ga[i][0][1]);
      t[2] = (short)f2bf(ga[i][0][2]); t[3] = (short)f2bf(ga[i][0][3]);
      t[4] = (short)f2bf(ga[i][1][0]); t[5] = (short)f2bf(ga[i][1][1]);
      t[6] = (short)f2bf(ga[i][1][2]); t[7] = (short)f2bf(ga[i][1][3]);
      *(bf16x8*)&As[row * 64 + ((cc ^ (row & 7)) << 3)] = t;
    }

    asm volatile("s_waitcnt vmcnt(0) lgkmcnt(0)" ::: "memory");  // B landed, A writes done
    __syncthreads();                                             // tile visible

    #pragma unroll
    for (int kk = 0; kk < 2; ++kk) {
      bf16x8 av[8], bv[4];
      #pragma unroll
      for (int mi = 0; mi < 8; ++mi)
        av[mi] = *(const bf16x8*)&As[(wr * 128 + mi * 16 + rlo) * 64 + swz[kk]];
      #pragma unroll
      for (int ni = 0; ni < 4; ++ni)
        bv[ni] = *(const bf16x8*)&Bs[(wc * 64 + ni * 16 + rlo) * 64 + swz[kk]];
      __builtin_amdgcn_s_setprio(1);
      #pragma unroll
      for (int mi = 0; mi < 8; ++mi)
        #pragma unroll
        for (int ni = 0; ni < 4; ++ni)
          acc[mi][ni] = __builtin_amdgcn_mfma_f32_16x16x32_bf16(
              av[mi], bv[ni], acc[mi][ni], 0, 0, 0);
      __builtin_amdgcn_s_setprio(0);
    }

    __syncthreads();                 // all reads done before next tile's writes
  }

  // Epilogue: C/D layout col=lane&15, row=(lane>>4)*4+reg
  const int row0 = gm0 + wr * 128 + (lane >> 4) * 4;
  const int col0 = gn0 + wc * 64 + (lane & 15);
  #pragma unroll
  for (int mi = 0; mi < 8; ++mi)
    #pragma unroll
    for (int ni = 0; ni < 4; ++ni)
      #pragma unroll
      for (int r = 0; r < 4; ++r)
        out[(size_t)(row0 + mi * 16 + r) * E_N + (col0 + ni * 16)] = acc[mi][ni][r];
}

extern "C" void kernel_launch(void* const* d_in, const int* in_sizes, int n_in,
                              void* d_out, int out_size, void* d_ws, size_t ws_size,
                              hipStream_t stream) {
  const float* img = (const float*)d_in[0];
  const int*   seg = (const int*)d_in[1];
  const float* cw  = (const float*)d_in[2];
  float* out = (float*)d_out;
  char* ws = (char*)d_ws;

  unsigned long long* partials = (unsigned long long*)ws;    // 8,388,608 B
  unsigned short* Bmat = (unsigned short*)(ws + 8388608);    // 1,179,648 B

  k_accum_convw<<<1600, 256, 0, stream>>>(seg, partials, cw, Bmat);
  k_gemmfg<<<768, 512, 0, stream>>>(img, partials, Bmat, out);
}